// Round 1
// 63.051 us; speedup vs baseline: 1.0048x; 1.0048x over previous
//
#include <hip/hip_runtime.h>
#include <math.h>

// QCONV2d 5x5: out[b,c,h,w] = prod_{p=1..24} cos(x_patch[p] + w[p])
// Tan-folded form: cos(x+w_p) = cos(w_p) * (cos(x) - sin(x)*tan(w_p))
//   => out = C * prod_p (cx_p - sx_p * tw_p),  C = prod_{p=1..24} cos(w_p).
// Per-term cost drops 3 VALU -> 2 VALU (v_fma with -src modifier + v_mul).
// sincos(pixel) once -> LDS float2 (cos,sin); tan(w)/C once per lane ->
// v_readlane -> wave-uniform SGPRs.
// R3 compute structure retained (TR=32, 1024 blocks, 16 waves/CU,
// 3 aligned ds_read_b128 per neighborhood row). Column halo is ALWAYS
// zero-pad -> (1,0) = term 1.0 with cos(w_p) carried by C; row-OOB staged as
// zeroed vector -> sincos(0) = (0,1) = exact pad value.

#define TR   32                 // output rows per block strip
#define SMR  (TR + 4)           // 36 staged rows
#define SMC  (64 + 4)           // 68 staged cols (544 B/row, 16B-multiple)

__device__ __forceinline__ float rdlane(float v, int lane) {
    return __uint_as_float(__builtin_amdgcn_readlane(__float_as_uint(v), lane));
}

__global__ __launch_bounds__(256)
void qconv5x5_kernel(const float* __restrict__ x, const float* __restrict__ w,
                     float* __restrict__ out)
{
    __shared__ alignas(16) float2 sm[SMR][SMC];   // (cos,sin), 19.6 KB

    const int tid   = threadIdx.x;
    const int bid   = blockIdx.x;
    const int plane = bid >> 1;              // 512 planes
    const int r0    = (bid & 1) * TR;        // strip start row: 0 or 32

    // --- w-trig: one sincos per lane; broadcast tan(w_p) and
    //     C = prod_{p=1..24} cos(w_p) via readlane -> wave-uniform SGPRs ---
    const int lane = tid & 63;
    float sv, cv;
    __sincosf(w[lane < 25 ? lane : 0], &sv, &cv);
    const float tv = sv / cv;                // IEEE divide, once per lane
    float tw[25];
    float C = 1.0f;
#pragma unroll
    for (int p = 0; p < 25; ++p) {
        tw[p] = rdlane(tv, p);
        if (p >= 1) C *= rdlane(cv, p);      // reference skips patch 0
    }

    // --- staging (unchanged from R3-best) ---
    const float* xp = x + plane * 64 * 64;

    // (a) column halo: cols 0,1,66,67 of every staged row = pad (1,0)
    if (tid < SMR * 4) {                     // 144 threads
        const int rr = tid >> 2;
        const int e  = tid & 3;
        const int cc = (e < 2) ? e : 64 + e; // 0,1,66,67
        sm[rr][cc] = make_float2(1.0f, 0.0f);
    }

    // (b) interior: 36 rows x 16 aligned float4 slots; row-OOB -> zeros
    for (int i = tid; i < SMR * 16; i += 256) {
        const int rr = i >> 4;               // 0..35
        const int ss = i & 15;               // 0..15
        const int gr = r0 + rr - 2;
        float4 px = make_float4(0.f, 0.f, 0.f, 0.f);
        if ((unsigned)gr < 64u)
            px = *reinterpret_cast<const float4*>(xp + gr * 64 + 4 * ss);
        float s0, c0, s1, c1, s2, c2, s3, c3;
        __sincosf(px.x, &s0, &c0);
        __sincosf(px.y, &s1, &c1);
        __sincosf(px.z, &s2, &c2);
        __sincosf(px.w, &s3, &c3);
        float2* dst = &sm[rr][4 * ss + 2];   // 16B-aligned
        dst[0] = make_float2(c0, s0);
        dst[1] = make_float2(c1, s1);
        dst[2] = make_float2(c2, s2);
        dst[3] = make_float2(c3, s3);
    }
    __syncthreads();

    // --- compute (R3 structure): col-pair cp, row-group rq (4 rows) ---
    const int cp = tid & 31;         // 0..31
    const int rq = tid >> 5;         // 0..7, output local rows rq*4..rq*4+3

    float prod[4][2];
#pragma unroll
    for (int ro = 0; ro < 4; ++ro) { prod[ro][0] = C; prod[ro][1] = C; }

    // 8 neighborhood rows feed 4 output rows; output local row rl = rq*4+ro
    // uses staged rows rl..rl+4 (staged row 0 = global row r0-2).
#pragma unroll
    for (int nr = 0; nr < 8; ++nr) {
        const int tr = rq * 4 + nr;
        const float4* rowp = reinterpret_cast<const float4*>(&sm[tr][0]);
        float4 f0 = rowp[cp], f1 = rowp[cp + 1], f2 = rowp[cp + 2];
        float2 arr6[6] = { make_float2(f0.x, f0.y), make_float2(f0.z, f0.w),
                           make_float2(f1.x, f1.y), make_float2(f1.z, f1.w),
                           make_float2(f2.x, f2.y), make_float2(f2.z, f2.w) };
#pragma unroll
        for (int ro = 0; ro < 4; ++ro) {
            const int di = nr - ro;
            if (di < 0 || di > 4) continue;
#pragma unroll
            for (int dj = 0; dj < 5; ++dj) {
                const int p = di * 5 + dj;
#pragma unroll
                for (int pa = 0; pa < 2; ++pa) {
                    if (p == 0) continue;          // reference skips patch 0
                    const float2 v = arr6[dj + pa];
                    // term = cx - sx*tan(w_p); 1 fma (free neg mod) + 1 mul
                    prod[ro][pa] *= fmaf(-v.y, tw[p], v.x);
                }
            }
        }
    }

    float2* op = reinterpret_cast<float2*>(
        out + plane * 64 * 64 + (r0 + rq * 4) * 64 + 2 * cp);
#pragma unroll
    for (int ro = 0; ro < 4; ++ro)
        op[ro * 32] = make_float2(prod[ro][0], prod[ro][1]);
}

extern "C" void kernel_launch(void* const* d_in, const int* in_sizes, int n_in,
                              void* d_out, int out_size, void* d_ws, size_t ws_size,
                              hipStream_t stream) {
    const float* x = (const float*)d_in[0];   // [32,16,64,64] f32
    const float* w = (const float*)d_in[1];   // [25] f32
    float* out = (float*)d_out;               // [32,16,64,64] f32
    (void)in_sizes; (void)n_in; (void)out_size; (void)d_ws; (void)ws_size;

    dim3 grid(512 * (64 / TR));               // 1024 blocks
    dim3 block(256);
    qconv5x5_kernel<<<grid, block, 0, stream>>>(x, w, out);
}

// Round 2
// 62.210 us; speedup vs baseline: 1.0184x; 1.0135x over previous
//
#include <hip/hip_runtime.h>
#include <math.h>

// QCONV2d 5x5: out[b,c,h,w] = prod_{p=1..24} cos(x_patch[p] + w[p])
// Tan-folded form: cos(x+w_p) = cos(w_p) * (cos(x) - sin(x)*tan(w_p))
//   => out = C * prod_p (cx_p - sx_p * tw_p),  C = prod_{p=1..24} cos(w_p).
// R4: latency-focused staging. All global loads (w + 3 x float4 slots) issue
// back-to-back at kernel entry; the w-trig prologue (sincos, divide, 50
// readlanes) executes while the x loads are in flight; sincos+LDS-write
// consumes afterwards. One cold-miss latency exposure instead of four
// (L2/L3 are dirty/flushed by the harness's 256 MiB poison fill, so every
// x read is an HBM miss). Compute phase = R3 structure, tan-folded.

#define TR   32                 // output rows per block strip
#define SMR  (TR + 4)           // 36 staged rows
#define SMC  (64 + 4)           // 68 staged cols (544 B/row, 16B-multiple)

__device__ __forceinline__ float rdlane(float v, int lane) {
    return __uint_as_float(__builtin_amdgcn_readlane(__float_as_uint(v), lane));
}

__global__ __launch_bounds__(256)
void qconv5x5_kernel(const float* __restrict__ x, const float* __restrict__ w,
                     float* __restrict__ out)
{
    __shared__ alignas(16) float2 sm[SMR][SMC];   // (cos,sin), 19.6 KB

    const int tid   = threadIdx.x;
    const int bid   = blockIdx.x;
    const int plane = bid >> 1;              // 512 planes
    const int r0    = (bid & 1) * TR;        // strip start row: 0 or 32
    const int lane  = tid & 63;

    const float* xp = x + plane * 64 * 64;

    // ---- issue ALL global loads up front: w first, then 3 x-slots ----
    const float wv = w[lane < 25 ? lane : 0];

    // staging slots: i = tid, tid+256, tid+512(<576); rr = i>>4, ss = i&15.
    // (i+256)&15 == i&15, so ss is shared.
    float4 p0 = make_float4(0.f, 0.f, 0.f, 0.f), p1 = p0, p2 = p0;
    const int ss  = tid & 15;                // 0..15
    const int rr0 = tid >> 4;                // 0..15
    const int rr1 = rr0 + 16;                // 16..31
    const int rr2 = rr0 + 32;                // 32..35 (tid<64 only)
    const int gr0 = r0 + rr0 - 2;
    const int gr1 = r0 + rr1 - 2;
    const int gr2 = r0 + rr2 - 2;
    const bool has2 = (tid < 64);
    if ((unsigned)gr0 < 64u)
        p0 = *reinterpret_cast<const float4*>(xp + gr0 * 64 + 4 * ss);
    if ((unsigned)gr1 < 64u)
        p1 = *reinterpret_cast<const float4*>(xp + gr1 * 64 + 4 * ss);
    if (has2 && (unsigned)gr2 < 64u)
        p2 = *reinterpret_cast<const float4*>(xp + gr2 * 64 + 4 * ss);

    // ---- column halo: cols 0,1,66,67 of every staged row = pad (1,0) ----
    // (independent of the in-flight loads)
    if (tid < SMR * 4) {                     // 144 threads
        const int rr = tid >> 2;
        const int e  = tid & 3;
        const int cc = (e < 2) ? e : 64 + e; // 0,1,66,67
        sm[rr][cc] = make_float2(1.0f, 0.0f);
    }

    // ---- w-trig prologue: overlaps the x-load latency ----
    float sv, cv;
    __sincosf(wv, &sv, &cv);
    const float tv = sv / cv;                // IEEE divide, once per lane
    float tw[25];
    float C = 1.0f;
#pragma unroll
    for (int p = 0; p < 25; ++p) {
        tw[p] = rdlane(tv, p);
        if (p >= 1) C *= rdlane(cv, p);      // reference skips patch 0
    }

    // ---- consume loads: sincos -> LDS (row-OOB slots hold zeros ->
    //      sincos(0) = (0,1) = exact pad value) ----
    {
        float s0, c0, s1, c1, s2, c2, s3, c3;
        __sincosf(p0.x, &s0, &c0);  __sincosf(p0.y, &s1, &c1);
        __sincosf(p0.z, &s2, &c2);  __sincosf(p0.w, &s3, &c3);
        float2* d = &sm[rr0][4 * ss + 2];    // 16B-aligned
        d[0] = make_float2(c0, s0);  d[1] = make_float2(c1, s1);
        d[2] = make_float2(c2, s2);  d[3] = make_float2(c3, s3);
    }
    {
        float s0, c0, s1, c1, s2, c2, s3, c3;
        __sincosf(p1.x, &s0, &c0);  __sincosf(p1.y, &s1, &c1);
        __sincosf(p1.z, &s2, &c2);  __sincosf(p1.w, &s3, &c3);
        float2* d = &sm[rr1][4 * ss + 2];
        d[0] = make_float2(c0, s0);  d[1] = make_float2(c1, s1);
        d[2] = make_float2(c2, s2);  d[3] = make_float2(c3, s3);
    }
    if (has2) {
        float s0, c0, s1, c1, s2, c2, s3, c3;
        __sincosf(p2.x, &s0, &c0);  __sincosf(p2.y, &s1, &c1);
        __sincosf(p2.z, &s2, &c2);  __sincosf(p2.w, &s3, &c3);
        float2* d = &sm[rr2][4 * ss + 2];
        d[0] = make_float2(c0, s0);  d[1] = make_float2(c1, s1);
        d[2] = make_float2(c2, s2);  d[3] = make_float2(c3, s3);
    }
    __syncthreads();

    // ---- compute (R3 structure): col-pair cp, row-group rq (4 rows) ----
    const int cp = tid & 31;         // 0..31
    const int rq = tid >> 5;         // 0..7, output local rows rq*4..rq*4+3

    float prod[4][2];
#pragma unroll
    for (int ro = 0; ro < 4; ++ro) { prod[ro][0] = C; prod[ro][1] = C; }

    // 8 neighborhood rows feed 4 output rows; output local row rl = rq*4+ro
    // uses staged rows rl..rl+4 (staged row 0 = global row r0-2).
#pragma unroll
    for (int nr = 0; nr < 8; ++nr) {
        const int tr = rq * 4 + nr;
        const float4* rowp = reinterpret_cast<const float4*>(&sm[tr][0]);
        float4 f0 = rowp[cp], f1 = rowp[cp + 1], f2 = rowp[cp + 2];
        float2 arr6[6] = { make_float2(f0.x, f0.y), make_float2(f0.z, f0.w),
                           make_float2(f1.x, f1.y), make_float2(f1.z, f1.w),
                           make_float2(f2.x, f2.y), make_float2(f2.z, f2.w) };
#pragma unroll
        for (int ro = 0; ro < 4; ++ro) {
            const int di = nr - ro;
            if (di < 0 || di > 4) continue;
#pragma unroll
            for (int dj = 0; dj < 5; ++dj) {
                const int p = di * 5 + dj;
#pragma unroll
                for (int pa = 0; pa < 2; ++pa) {
                    if (p == 0) continue;          // reference skips patch 0
                    const float2 v = arr6[dj + pa];
                    // term = cx - sx*tan(w_p); 1 fma (free neg mod) + 1 mul
                    prod[ro][pa] *= fmaf(-v.y, tw[p], v.x);
                }
            }
        }
    }

    float2* op = reinterpret_cast<float2*>(
        out + plane * 64 * 64 + (r0 + rq * 4) * 64 + 2 * cp);
#pragma unroll
    for (int ro = 0; ro < 4; ++ro)
        op[ro * 32] = make_float2(prod[ro][0], prod[ro][1]);
}

extern "C" void kernel_launch(void* const* d_in, const int* in_sizes, int n_in,
                              void* d_out, int out_size, void* d_ws, size_t ws_size,
                              hipStream_t stream) {
    const float* x = (const float*)d_in[0];   // [32,16,64,64] f32
    const float* w = (const float*)d_in[1];   // [25] f32
    float* out = (float*)d_out;               // [32,16,64,64] f32
    (void)in_sizes; (void)n_in; (void)out_size; (void)d_ws; (void)ws_size;

    dim3 grid(512 * (64 / TR));               // 1024 blocks
    dim3 block(256);
    qconv5x5_kernel<<<grid, block, 0, stream>>>(x, w, out);
}